// Round 3
// baseline (88.485 us; speedup 1.0000x reference)
//
#include <hip/hip_runtime.h>
#include <math.h>

#define NWIRES 6
#define DIM 64
#define NTOK 32768            // B*T = 16*2048
#define NBATCH 16
#define TPB 2048              // tokens per batch
#define NMOM 16               // Taylor order: exp(az), |az|<=sqrt(6); rem ~8e-8
#define SQRT6F 2.4494897427831781f
#define APAD 76               // LDS row stride (ushorts), conflict-benign (R12)

typedef short bf16x8 __attribute__((ext_vector_type(8)));
typedef float f32x4  __attribute__((ext_vector_type(4)));

__device__ __forceinline__ unsigned f2bfbits(float f) {   // RNE fp32->bf16 bits
    unsigned u = __float_as_uint(f);
    return (u + 0x7FFF + ((u >> 16) & 1)) >> 16;
}
__device__ __forceinline__ float bfbits2f(unsigned b) {
    return __uint_as_float(b << 16);
}
__device__ __forceinline__ float pswap(float v) { return __shfl_xor(v, 1, 64); }

// ---------------------------------------------------------------------------
// Kernel 1: fused A-build + MFMA sim.  Grid (128, 3): 256-token tile, circuit.
// R16: back to the best-measured R13 shape (inline A-build, 3 kernels,
// 384 blocks -- R14/R15 proved staging+extra kernel costs +2.2us and block
// count is neutral).  NEW vs R13: the MFMA loop is restructured so each
// A-fragment is read from LDS ONCE and applied to TWO chunk-groups
// (ds_read_b64 per wave: 256 -> 128).  Both pair accumulators stay live
// (~160 VGPR est., still 3 waves/SIMD, zero spill expected).  Per-acc MFMA
// order is unchanged -> zq/kv bitwise identical to R13.
// ---------------------------------------------------------------------------
__global__ __attribute__((amdgpu_waves_per_eu(1, 4)))
__launch_bounds__(256) void qsa_sim(
        const float* __restrict__ x,
        const float* __restrict__ pq,
        const float* __restrict__ pk,
        const float* __restrict__ pv,
        float* __restrict__ zq,
        float* __restrict__ kv) {
    __shared__ unsigned short sAh[128 * APAD];   // 19456 B
    __shared__ unsigned short sAl[128 * APAD];   // 19456 B
    __shared__ float sTc[64], sTs[64], sP[24];
    int tid = threadIdx.x;
    int tbase = blockIdx.x * 256;
    int circ = blockIdx.y;
    const float* p = (circ == 0) ? pq : (circ == 1 ? pk : pv);

    // ---- issue pair-0 X loads first (cg 0 and 1; overlap with build) ----
    int lane = tid & 63, wv = tid >> 6;
    int q4 = lane >> 4, c16 = lane & 15;
    float4 rw[8];
#pragma unroll
    for (int cg = 0; cg < 2; ++cg) {
        const float* xr = x + ((size_t)(tbase + wv * 64 + cg * 16 + c16)) * 64;
#pragma unroll
        for (int ks = 0; ks < 2; ++ks) {
            rw[cg * 4 + ks * 2 + 0] = *(const float4*)(xr + ks * 32 + q4 * 8);
            rw[cg * 4 + ks * 2 + 1] = *(const float4*)(xr + ks * 32 + q4 * 8 + 4);
        }
    }

    // ---- angle tables (threads 0..63) ----
    if (tid < 64) {
        int b = tid;
        float d = 0.f;
#pragma unroll
        for (int j = 0; j < 6; ++j)
            d += 0.5f * p[j] * ((b & (32 >> j)) ? -1.f : 1.f);
        float sd, cd;
        sincosf(d, &sd, &cd);
        sTc[b] = cd;
        sTs[b] = sd;
        if (b < 12) {                     // p[6..11]=RY0, p[12..17]=RY1
            float s, cc;
            sincosf(0.5f * p[6 + b], &s, &cc);
            sP[b * 2 + 0] = cc;
            sP[b * 2 + 1] = s;
        }
    }
    __syncthreads();

    // ---- A-build: thread (ph, k, h) evolves 32-float half-column (R12) ----
    {
        int ph = tid >> 7;                // 0: cos rows, 1: sin rows
        int k  = (tid >> 1) & 63;         // column
        int h  = tid & 1;                 // bit5 (value 32) of row index
        const float* sTx = ph ? sTs : sTc;
        float v[32];
#pragma unroll
        for (int i = 0; i < 32; ++i) {
            int g = h * 32 + i;
            v[i] = (__popc(g & k) & 1) ? -sTx[g] : sTx[g];   // diag(T) W e_k
        }
        // Walsh stage M=32 (split): lo'=lo+hi, hi'=lo-hi
#pragma unroll
        for (int i = 0; i < 32; ++i) {
            float pv_ = pswap(v[i]);
            v[i] = h ? (pv_ - v[i]) : (v[i] + pv_);
        }
        // Walsh stages M=16..1 (local)
#pragma unroll
        for (int M = 16; M >= 1; M >>= 1) {
#pragma unroll
            for (int i = 0; i < 32; ++i) {
                if (i & M) continue;
                int j = i | M;
                float a = v[i], b = v[j];
                v[i] = a + b; v[j] = a - b;
            }
        }
        // RY0 then CNOT ring then RY1
#pragma unroll
        for (int layer = 0; layer < 2; ++layer) {
            const float* Pl = sP + layer * 12;
            // wire0 (split): new = c*mine + (h? +s : -s)*partner
            {
                float c = Pl[0], ss = h ? Pl[1] : -Pl[1];
#pragma unroll
                for (int i = 0; i < 32; ++i) {
                    float pv_ = pswap(v[i]);
                    v[i] = c * v[i] + ss * pv_;
                }
            }
            // wires 1..5 local (masks 16,8,4,2,1)
#pragma unroll
            for (int w = 1; w < 6; ++w) {
                int M = 32 >> w;
                float c = Pl[w * 2], s = Pl[w * 2 + 1];
#pragma unroll
                for (int i = 0; i < 32; ++i) {
                    if (i & M) continue;
                    int j = i | M;
                    float a = v[i], b = v[j];
                    v[i] = c * a - s * b;
                    v[j] = s * a + c * b;
                }
            }
            if (layer == 0) {
                // CNOT(0,1): control bit32 (h), target 16 -> h=1 swaps i<->i|16
#pragma unroll
                for (int i = 0; i < 16; ++i) {
                    int j = i | 16;
                    float a = v[i], b = v[j];
                    v[i] = h ? b : a;
                    v[j] = h ? a : b;
                }
                // CNOT(1,2)(2,3)(3,4)(4,5): local renames
#pragma unroll
                for (int w = 1; w < 5; ++w) {
                    int MC = 32 >> w, MT = MC >> 1;
#pragma unroll
                    for (int i = 0; i < 32; ++i) {
                        if (!(i & MC) || (i & MT)) continue;
                        int j = i | MT;
                        float t = v[i]; v[i] = v[j]; v[j] = t;
                    }
                }
                // CNOT(5,0): control bit0, target bit32 -> odd i exchange lanes
#pragma unroll
                for (int i = 1; i < 32; i += 2) v[i] = pswap(v[i]);
            }
        }
        // pack bf16 hi/lo into LDS
#pragma unroll
        for (int i = 0; i < 32; ++i) {
            int row = ph * 64 + h * 32 + i;
            unsigned hb = f2bfbits(v[i]);
            unsigned lb = f2bfbits(v[i] - bfbits2f(hb));
            sAh[row * APAD + k] = (unsigned short)hb;
            sAl[row * APAD + k] = (unsigned short)lb;
        }
    }
    __syncthreads();

    // ---- MFMA: 2 pairs x 2 chunk-groups; A-fragments read once per pair ----
    bf16x8 xh[2][2], xl[2][2];
#pragma unroll 1
    for (int pr = 0; pr < 2; ++pr) {
        // convert this pair's raws -> fragments
#pragma unroll
        for (int cg = 0; cg < 2; ++cg) {
#pragma unroll
            for (int ks = 0; ks < 2; ++ks) {
                float4 f0 = rw[cg * 4 + ks * 2], f1 = rw[cg * 4 + ks * 2 + 1];
                float ff[8] = {f0.x, f0.y, f0.z, f0.w, f1.x, f1.y, f1.z, f1.w};
#pragma unroll
                for (int e = 0; e < 8; ++e) {
                    unsigned hb = f2bfbits(ff[e]);
                    unsigned lb = f2bfbits(ff[e] - bfbits2f(hb));
                    xh[cg][ks][e] = (short)hb;
                    xl[cg][ks][e] = (short)lb;
                }
            }
        }
        // prefetch next pair's raws (overlaps MFMAs below)
        if (pr == 0) {
#pragma unroll
            for (int cg = 0; cg < 2; ++cg) {
                const float* xr = x + ((size_t)(tbase + wv * 64 + (2 + cg) * 16 + c16)) * 64;
#pragma unroll
                for (int ks = 0; ks < 2; ++ks) {
                    rw[cg * 4 + ks * 2 + 0] = *(const float4*)(xr + ks * 32 + q4 * 8);
                    rw[cg * 4 + ks * 2 + 1] = *(const float4*)(xr + ks * 32 + q4 * 8 + 4);
                }
            }
        }

        f32x4 acc[2][8];
#pragma unroll
        for (int cg = 0; cg < 2; ++cg)
#pragma unroll
            for (int mt = 0; mt < 8; ++mt) acc[cg][mt] = (f32x4){0.f, 0.f, 0.f, 0.f};

#pragma unroll
        for (int mt = 0; mt < 8; ++mt) {
            int r = mt * 16 + c16;               // A-op row m
#pragma unroll
            for (int ks = 0; ks < 2; ++ks) {
                const uint2* ph_ = (const uint2*)(&sAh[r * APAD + ks * 32 + q4 * 8]);
                const uint2* pl_ = (const uint2*)(&sAl[r * APAD + ks * 32 + q4 * 8]);
                union { uint2 u[2]; bf16x8 v; } ua, ub;
                ua.u[0] = ph_[0]; ua.u[1] = ph_[1];
                ub.u[0] = pl_[0]; ub.u[1] = pl_[1];
                bf16x8 ah = ua.v, al = ub.v;
#pragma unroll
                for (int cg = 0; cg < 2; ++cg) {
                    acc[cg][mt] = __builtin_amdgcn_mfma_f32_16x16x32_bf16(ah, xh[cg][ks], acc[cg][mt], 0, 0, 0);
                    acc[cg][mt] = __builtin_amdgcn_mfma_f32_16x16x32_bf16(ah, xl[cg][ks], acc[cg][mt], 0, 0, 0);
                    acc[cg][mt] = __builtin_amdgcn_mfma_f32_16x16x32_bf16(al, xh[cg][ks], acc[cg][mt], 0, 0, 0);
                }
            }
        }

        // epilogue per chunk-group (R12-verified math)
#pragma unroll
        for (int cg = 0; cg < 2; ++cg) {
            float n = 0.f, s0 = 0.f, s1 = 0.f, s2 = 0.f, s3 = 0.f, s4 = 0.f, s5 = 0.f;
            float f2 = (q4 < 2) ? 1.f : 0.f;         // r bit3 == 0
            float f3 = (q4 & 1) ? 0.f : 1.f;         // r bit2 == 0
#pragma unroll
            for (int mt = 0; mt < 4; ++mt) {
#pragma unroll
                for (int rg = 0; rg < 4; ++rg) {
                    float dc = acc[cg][mt][rg];      // row r = mt*16 + q4*4 + rg
                    float ds = acc[cg][mt + 4][rg];  // row r + 64
                    float pp = dc * dc + ds * ds;
                    n += pp;
                    if (!(mt & 2)) s0 += pp;         // bit5
                    if (!(mt & 1)) s1 += pp;         // bit4
                    s2 += f2 * pp;                   // bit3
                    s3 += f3 * pp;                   // bit2
                    if (!(rg & 2)) s4 += pp;         // bit1
                    if (!(rg & 1)) s5 += pp;         // bit0
                }
            }
#pragma unroll
            for (int d = 16; d <= 32; d <<= 1) {
                n  += __shfl_xor(n,  d, 64);
                s0 += __shfl_xor(s0, d, 64);
                s1 += __shfl_xor(s1, d, 64);
                s2 += __shfl_xor(s2, d, 64);
                s3 += __shfl_xor(s3, d, 64);
                s4 += __shfl_xor(s4, d, 64);
                s5 += __shfl_xor(s5, d, 64);
            }
            if (q4 == 0) {
                int t = tbase + wv * 64 + (pr * 2 + cg) * 16 + c16;
                float inv = 1.0f / n;
                if (circ == 0) {
                    zq[t] = SQRT6F * (2.f * s0 - n) * inv;   // a_t
                } else if (circ == 1) {
                    kv[(size_t)t * 8] = (2.f * s0 - n) * inv;
                } else {
                    float* o = kv + (size_t)t * 8;
                    o[1] = (2.f*s0 - n) * inv;
                    o[2] = (2.f*s1 - n) * inv;
                    o[3] = (2.f*s2 - n) * inv;
                    o[4] = (2.f*s3 - n) * inv;
                    o[5] = (2.f*s4 - n) * inv;
                    o[6] = (2.f*s5 - n) * inv;
                    o[7] = 0.f;
                }
            }
        }
    }
}

// ---------------------------------------------------------------------------
// Kernel 2: partial power moments per (batch, chunk-of-256).
// S_m = sum z^m, H_{m,w} = sum z^m * v_w, m=0..15.
// R16: butterfly (672 dependent ds_swizzle+add, 6-stage latency chain)
// replaced by LDS-transpose reduce: each lane writes its 112 accumulators
// to a padded LDS row (stride 113 -> conflict-free), then lane l sums
// columns l and l+64.  ~2.8x fewer LDS ops, no dependency chain.
// ---------------------------------------------------------------------------
__global__ __attribute__((amdgpu_waves_per_eu(1, 2)))
__launch_bounds__(64) void qsa_moments_partial(
        const float* __restrict__ kv,
        float* __restrict__ mpart) {
    __shared__ float sm[64 * 113];    // 28928 B
    int blk = blockIdx.x;             // 16 batches * 8 chunks
    int b = blk >> 3, c = blk & 7;
    int lane = threadIdx.x;
    float S[NMOM], H[NMOM][6];
#pragma unroll
    for (int m = 0; m < NMOM; ++m) {
        S[m] = 0.f;
#pragma unroll
        for (int w = 0; w < 6; ++w) H[m][w] = 0.f;
    }
    const float* base = kv + ((size_t)(b * TPB + c * 256)) * 8;
#pragma unroll
    for (int r = 0; r < 4; ++r) {
        const float4* e = (const float4*)(base + (size_t)(r * 64 + lane) * 8);
        float4 e0 = e[0], e1 = e[1];
        float z = e0.x;
        float v0 = e0.y, v1 = e0.z, v2 = e0.w, v3 = e1.x, v4 = e1.y, v5 = e1.z;
        float pw = 1.f;
#pragma unroll
        for (int m = 0; m < NMOM; ++m) {
            S[m] += pw;
            H[m][0] += pw * v0; H[m][1] += pw * v1; H[m][2] += pw * v2;
            H[m][3] += pw * v3; H[m][4] += pw * v4; H[m][5] += pw * v5;
            pw *= z;
        }
    }
    // write 112 values to this lane's padded LDS row (order: m*7 + {S,H0..H5})
    float* row = sm + lane * 113;
#pragma unroll
    for (int m = 0; m < NMOM; ++m) {
        row[m * 7 + 0] = S[m];
        row[m * 7 + 1] = H[m][0]; row[m * 7 + 2] = H[m][1];
        row[m * 7 + 3] = H[m][2]; row[m * 7 + 4] = H[m][3];
        row[m * 7 + 5] = H[m][4]; row[m * 7 + 6] = H[m][5];
    }
    __syncthreads();
    // column sums: lane l reduces value-index l and l+64
#pragma unroll
    for (int vbase = 0; vbase < 2; ++vbase) {
        int v = vbase * 64 + lane;
        if (v < 112) {
            float s = 0.f;
#pragma unroll
            for (int r = 0; r < 64; ++r) s += sm[r * 113 + v];
            mpart[(size_t)blk * 112 + v] = s;
        }
    }
}

// ---------------------------------------------------------------------------
// Kernel 3: fused combine + per-token evaluation (one block = 256 tokens).
// den = sum_m p_m S_m, out_w = sum_m p_m H_mw, p_m = a^m/m!.
// ---------------------------------------------------------------------------
__global__ __launch_bounds__(256) void qsa_eval(
        const float* __restrict__ zq,
        const float* __restrict__ mpart,
        float* __restrict__ out) {
    __shared__ float sm[112];
    int bk = blockIdx.x;                      // 128 blocks
    int b = bk >> 3;                          // 8 blocks per batch
    int tid = threadIdx.x;
    if (tid < 112) {
        float s = 0.f;
#pragma unroll
        for (int c = 0; c < 8; ++c) s += mpart[(size_t)(b * 8 + c) * 112 + tid];
        sm[tid] = s;
    }
    __syncthreads();

    int t = bk * 256 + tid;
    float a = zq[t];
    float den = 0.f, o0 = 0.f, o1 = 0.f, o2 = 0.f, o3 = 0.f, o4 = 0.f, o5 = 0.f;
    float pw = 1.f;
#pragma unroll
    for (int m = 0; m < NMOM; ++m) {
        const float* mm = sm + m * 7;
        den += pw * mm[0];
        o0 += pw * mm[1]; o1 += pw * mm[2]; o2 += pw * mm[3];
        o3 += pw * mm[4]; o4 += pw * mm[5]; o5 += pw * mm[6];
        pw *= a * (1.0f / (m + 1));           // p_{m+1} = p_m * a/(m+1)
    }
    float inv = 1.0f / den;
    float* o = out + (size_t)t * 6;
    float2* o2p = (float2*)o;                 // t*24B is 8-aligned
    o2p[0] = make_float2(o0 * inv, o1 * inv);
    o2p[1] = make_float2(o2 * inv, o3 * inv);
    o2p[2] = make_float2(o4 * inv, o5 * inv);
}

// ---------------------------------------------------------------------------
extern "C" void kernel_launch(void* const* d_in, const int* in_sizes, int n_in,
                              void* d_out, int out_size, void* d_ws, size_t ws_size,
                              hipStream_t stream) {
    const float* x  = (const float*)d_in[0];
    const float* pq = (const float*)d_in[1];
    const float* pk = (const float*)d_in[2];
    const float* pv = (const float*)d_in[3];
    float* w = (float*)d_ws;
    // ws (floats): zq[32768] | kv[262144] | mpart[14336]
    float* zq    = w;
    float* kv    = zq + NTOK;
    float* mpart = kv + NTOK * 8;
    float* out   = (float*)d_out;

    qsa_sim<<<dim3(NTOK / 256, 3), 256, 0, stream>>>(x, pq, pk, pv, zq, kv);
    qsa_moments_partial<<<NBATCH * 8, 64, 0, stream>>>(kv, mpart);
    qsa_eval<<<NTOK / 256, 256, 0, stream>>>(zq, mpart, out);
}

// Round 4
// 85.436 us; speedup vs baseline: 1.0357x; 1.0357x over previous
//
#include <hip/hip_runtime.h>
#include <math.h>

#define NWIRES 6
#define DIM 64
#define NTOK 32768            // B*T = 16*2048
#define NBATCH 16
#define TPB 2048              // tokens per batch
#define NMOM 16               // Taylor order: exp(az), |az|<=sqrt(6); rem ~8e-8
#define SQRT6F 2.4494897427831781f
#define APAD 76               // LDS row stride (ushorts), conflict-benign (R12)
#define ZP 260                // zpow/vT row stride (floats): 16B-aligned rows

typedef short bf16x8 __attribute__((ext_vector_type(8)));
typedef float f32x4  __attribute__((ext_vector_type(4)));

__device__ __forceinline__ unsigned f2bfbits(float f) {   // RNE fp32->bf16 bits
    unsigned u = __float_as_uint(f);
    return (u + 0x7FFF + ((u >> 16) & 1)) >> 16;
}
__device__ __forceinline__ float bfbits2f(unsigned b) {
    return __uint_as_float(b << 16);
}
__device__ __forceinline__ float pswap(float v) { return __shfl_xor(v, 1, 64); }

// ---------------------------------------------------------------------------
// R17: dispatch-count attack.  Ledger R13-R16: four structurally different
// kernel sets all land at 86-88.5us; only measured signal is +2.2us per extra
// dispatch (R13->R14).  So: 3 kernels -> 2.  Grid (128, 2):
//   circ0 block bx: Q circuit for tokens [bx*256, bx*256+256) -> zq (as before)
//   circ1 block bx: K AND V circuits for the same tokens (x fragments shared),
//     then the chunk's moment partials computed IN-BLOCK -> mpart directly.
// kv array + qsa_moments_partial + one dispatch gap are deleted.  Total
// circuit work unchanged (384 sims in 256 blocks = 1/CU).  Sim MFMA math and
// accumulation order byte-identical to R12-R16.  Moments stay exact fp32
// (per-token power chain -> transposed LDS -> 224-thread (m,w)-parallel
// reduction); only the summation ORDER changes (absmax pinned at the bf16
// quantum 3.05e-5 across R13-R16 regardless of moment order).
// ---------------------------------------------------------------------------

// A-build device fn: angle tables + R12 half-column evolution -> sAh/sAl.
// Called by ALL threads of the block (contains barriers).
__device__ __forceinline__ void build_A(const float* __restrict__ p,
        unsigned short* sAh, unsigned short* sAl,
        float* sTc, float* sTs, float* sP, int tid) {
    if (tid < 64) {
        int b = tid;
        float d = 0.f;
#pragma unroll
        for (int j = 0; j < 6; ++j)
            d += 0.5f * p[j] * ((b & (32 >> j)) ? -1.f : 1.f);
        float sd, cd;
        sincosf(d, &sd, &cd);
        sTc[b] = cd;
        sTs[b] = sd;
        if (b < 12) {                     // p[6..11]=RY0, p[12..17]=RY1
            float s, cc;
            sincosf(0.5f * p[6 + b], &s, &cc);
            sP[b * 2 + 0] = cc;
            sP[b * 2 + 1] = s;
        }
    }
    __syncthreads();

    {
        int ph = tid >> 7;                // 0: cos rows, 1: sin rows
        int k  = (tid >> 1) & 63;         // column
        int h  = tid & 1;                 // bit5 (value 32) of row index
        const float* sTx = ph ? sTs : sTc;
        float v[32];
#pragma unroll
        for (int i = 0; i < 32; ++i) {
            int g = h * 32 + i;
            v[i] = (__popc(g & k) & 1) ? -sTx[g] : sTx[g];   // diag(T) W e_k
        }
        // Walsh stage M=32 (split): lo'=lo+hi, hi'=lo-hi
#pragma unroll
        for (int i = 0; i < 32; ++i) {
            float pv_ = pswap(v[i]);
            v[i] = h ? (pv_ - v[i]) : (v[i] + pv_);
        }
        // Walsh stages M=16..1 (local)
#pragma unroll
        for (int M = 16; M >= 1; M >>= 1) {
#pragma unroll
            for (int i = 0; i < 32; ++i) {
                if (i & M) continue;
                int j = i | M;
                float a = v[i], b = v[j];
                v[i] = a + b; v[j] = a - b;
            }
        }
        // RY0 then CNOT ring then RY1
#pragma unroll
        for (int layer = 0; layer < 2; ++layer) {
            const float* Pl = sP + layer * 12;
            {
                float c = Pl[0], ss = h ? Pl[1] : -Pl[1];
#pragma unroll
                for (int i = 0; i < 32; ++i) {
                    float pv_ = pswap(v[i]);
                    v[i] = c * v[i] + ss * pv_;
                }
            }
#pragma unroll
            for (int w = 1; w < 6; ++w) {
                int M = 32 >> w;
                float c = Pl[w * 2], s = Pl[w * 2 + 1];
#pragma unroll
                for (int i = 0; i < 32; ++i) {
                    if (i & M) continue;
                    int j = i | M;
                    float a = v[i], b = v[j];
                    v[i] = c * a - s * b;
                    v[j] = s * a + c * b;
                }
            }
            if (layer == 0) {
                // CNOT(0,1): control bit32 (h), target 16
#pragma unroll
                for (int i = 0; i < 16; ++i) {
                    int j = i | 16;
                    float a = v[i], b = v[j];
                    v[i] = h ? b : a;
                    v[j] = h ? a : b;
                }
                // CNOT(1,2)(2,3)(3,4)(4,5): local renames
#pragma unroll
                for (int w = 1; w < 5; ++w) {
                    int MC = 32 >> w, MT = MC >> 1;
#pragma unroll
                    for (int i = 0; i < 32; ++i) {
                        if (!(i & MC) || (i & MT)) continue;
                        int j = i | MT;
                        float t = v[i]; v[i] = v[j]; v[j] = t;
                    }
                }
                // CNOT(5,0): control bit0, target bit32
#pragma unroll
                for (int i = 1; i < 32; i += 2) v[i] = pswap(v[i]);
            }
        }
        // pack bf16 hi/lo into LDS
#pragma unroll
        for (int i = 0; i < 32; ++i) {
            int row = ph * 64 + h * 32 + i;
            unsigned hb = f2bfbits(v[i]);
            unsigned lb = f2bfbits(v[i] - bfbits2f(hb));
            sAh[row * APAD + k] = (unsigned short)hb;
            sAl[row * APAD + k] = (unsigned short)lb;
        }
    }
    __syncthreads();
}

__global__ __attribute__((amdgpu_waves_per_eu(1, 4)))
__launch_bounds__(256) void qsa_sim(
        const float* __restrict__ x,
        const float* __restrict__ pq,
        const float* __restrict__ pk,
        const float* __restrict__ pv,
        float* __restrict__ zq,
        float* __restrict__ mpart) {
    // slot0: Q or K matrices; slot1: V matrices (circ1 only).
    __shared__ __align__(16) unsigned short sAbuf[4 * 128 * APAD];  // 77824 B
    __shared__ float sTc[64], sTs[64], sP[24];
    __shared__ float zT[256];                       // K-circuit z per token
    __shared__ __align__(16) float vT[6 * ZP];      // V outputs, transposed
    __shared__ float sred[224];
    int tid = threadIdx.x;
    int tbase = blockIdx.x * 256;
    int circ = blockIdx.y;                          // 0: Q;  1: K+V+moments

    // ---- issue pair-0 X loads first (cg 0 and 1; overlap with build) ----
    int lane = tid & 63, wv = tid >> 6;
    int q4 = lane >> 4, c16 = lane & 15;
    float4 rw[8];
#pragma unroll
    for (int cg = 0; cg < 2; ++cg) {
        const float* xr = x + ((size_t)(tbase + wv * 64 + cg * 16 + c16)) * 64;
#pragma unroll
        for (int ks = 0; ks < 2; ++ks) {
            rw[cg * 4 + ks * 2 + 0] = *(const float4*)(xr + ks * 32 + q4 * 8);
            rw[cg * 4 + ks * 2 + 1] = *(const float4*)(xr + ks * 32 + q4 * 8 + 4);
        }
    }

    // ---- build A matrices ----
    int ncirc;
    if (circ == 0) {
        build_A(pq, sAbuf, sAbuf + 128 * APAD, sTc, sTs, sP, tid);
        ncirc = 1;
    } else {
        build_A(pk, sAbuf, sAbuf + 128 * APAD, sTc, sTs, sP, tid);
        build_A(pv, sAbuf + 2 * 128 * APAD, sAbuf + 3 * 128 * APAD,
                sTc, sTs, sP, tid);
        ncirc = 2;
    }

    // ---- MFMA: 2 pairs x 2 chunk-groups; x fragments shared across circs ----
    bf16x8 xh[2][2], xl[2][2];
#pragma unroll 1
    for (int pr = 0; pr < 2; ++pr) {
        // convert this pair's raws -> fragments (once per pair, shared K/V)
#pragma unroll
        for (int cg = 0; cg < 2; ++cg) {
#pragma unroll
            for (int ks = 0; ks < 2; ++ks) {
                float4 f0 = rw[cg * 4 + ks * 2], f1 = rw[cg * 4 + ks * 2 + 1];
                float ff[8] = {f0.x, f0.y, f0.z, f0.w, f1.x, f1.y, f1.z, f1.w};
#pragma unroll
                for (int e = 0; e < 8; ++e) {
                    unsigned hb = f2bfbits(ff[e]);
                    unsigned lb = f2bfbits(ff[e] - bfbits2f(hb));
                    xh[cg][ks][e] = (short)hb;
                    xl[cg][ks][e] = (short)lb;
                }
            }
        }
        // prefetch next pair's raws (overlaps MFMAs below)
        if (pr == 0) {
#pragma unroll
            for (int cg = 0; cg < 2; ++cg) {
                const float* xr = x + ((size_t)(tbase + wv * 64 + (2 + cg) * 16 + c16)) * 64;
#pragma unroll
                for (int ks = 0; ks < 2; ++ks) {
                    rw[cg * 4 + ks * 2 + 0] = *(const float4*)(xr + ks * 32 + q4 * 8);
                    rw[cg * 4 + ks * 2 + 1] = *(const float4*)(xr + ks * 32 + q4 * 8 + 4);
                }
            }
        }

#pragma unroll 1
        for (int cc = 0; cc < ncirc; ++cc) {
            const unsigned short* Ah = sAbuf + cc * (2 * 128 * APAD);
            const unsigned short* Al = Ah + 128 * APAD;

            f32x4 acc[2][8];
#pragma unroll
            for (int cg = 0; cg < 2; ++cg)
#pragma unroll
                for (int mt = 0; mt < 8; ++mt) acc[cg][mt] = (f32x4){0.f, 0.f, 0.f, 0.f};

#pragma unroll
            for (int mt = 0; mt < 8; ++mt) {
                int r = mt * 16 + c16;               // A-op row m
#pragma unroll
                for (int ks = 0; ks < 2; ++ks) {
                    const uint2* ph_ = (const uint2*)(&Ah[r * APAD + ks * 32 + q4 * 8]);
                    const uint2* pl_ = (const uint2*)(&Al[r * APAD + ks * 32 + q4 * 8]);
                    union { uint2 u[2]; bf16x8 v; } ua, ub;
                    ua.u[0] = ph_[0]; ua.u[1] = ph_[1];
                    ub.u[0] = pl_[0]; ub.u[1] = pl_[1];
                    bf16x8 ah = ua.v, al = ub.v;
#pragma unroll
                    for (int cg = 0; cg < 2; ++cg) {
                        acc[cg][mt] = __builtin_amdgcn_mfma_f32_16x16x32_bf16(ah, xh[cg][ks], acc[cg][mt], 0, 0, 0);
                        acc[cg][mt] = __builtin_amdgcn_mfma_f32_16x16x32_bf16(ah, xl[cg][ks], acc[cg][mt], 0, 0, 0);
                        acc[cg][mt] = __builtin_amdgcn_mfma_f32_16x16x32_bf16(al, xh[cg][ks], acc[cg][mt], 0, 0, 0);
                    }
                }
            }

            // epilogue per chunk-group (R12-verified math)
#pragma unroll
            for (int cg = 0; cg < 2; ++cg) {
                float n = 0.f, s0 = 0.f, s1 = 0.f, s2 = 0.f, s3 = 0.f, s4 = 0.f, s5 = 0.f;
                float f2 = (q4 < 2) ? 1.f : 0.f;         // r bit3 == 0
                float f3 = (q4 & 1) ? 0.f : 1.f;         // r bit2 == 0
#pragma unroll
                for (int mt = 0; mt < 4; ++mt) {
#pragma unroll
                    for (int rg = 0; rg < 4; ++rg) {
                        float dc = acc[cg][mt][rg];      // row r = mt*16 + q4*4 + rg
                        float ds = acc[cg][mt + 4][rg];  // row r + 64
                        float pp = dc * dc + ds * ds;
                        n += pp;
                        if (!(mt & 2)) s0 += pp;         // bit5
                        if (!(mt & 1)) s1 += pp;         // bit4
                        s2 += f2 * pp;                   // bit3
                        s3 += f3 * pp;                   // bit2
                        if (!(rg & 2)) s4 += pp;         // bit1
                        if (!(rg & 1)) s5 += pp;         // bit0
                    }
                }
#pragma unroll
                for (int d = 16; d <= 32; d <<= 1) {
                    n  += __shfl_xor(n,  d, 64);
                    s0 += __shfl_xor(s0, d, 64);
                    s1 += __shfl_xor(s1, d, 64);
                    s2 += __shfl_xor(s2, d, 64);
                    s3 += __shfl_xor(s3, d, 64);
                    s4 += __shfl_xor(s4, d, 64);
                    s5 += __shfl_xor(s5, d, 64);
                }
                if (q4 == 0) {
                    int tl = wv * 64 + (pr * 2 + cg) * 16 + c16;
                    float inv = 1.0f / n;
                    if (circ == 0) {
                        zq[tbase + tl] = SQRT6F * (2.f * s0 - n) * inv;  // a_t
                    } else if (cc == 0) {
                        zT[tl] = (2.f * s0 - n) * inv;                   // K z
                    } else {
                        vT[0 * ZP + tl] = (2.f * s0 - n) * inv;
                        vT[1 * ZP + tl] = (2.f * s1 - n) * inv;
                        vT[2 * ZP + tl] = (2.f * s2 - n) * inv;
                        vT[3 * ZP + tl] = (2.f * s3 - n) * inv;
                        vT[4 * ZP + tl] = (2.f * s4 - n) * inv;
                        vT[5 * ZP + tl] = (2.f * s5 - n) * inv;
                    }
                }
            }
        }
    }

    // ---- in-block moments (circ1 only): exact fp32, transposed reduction ----
    if (circ == 1) {
        __syncthreads();                 // zT/vT complete; sA matrices dead
        float* zpow = (float*)sAbuf;     // alias: 16 rows x ZP floats = 16.6 KB
        {
            float z = zT[tid];           // thread tid owns token tid
            float pw = 1.f;
#pragma unroll
            for (int m = 0; m < NMOM; ++m) { zpow[m * ZP + tid] = pw; pw *= z; }
        }
        __syncthreads();
        if (tid < 224) {                 // (m,w) x half: w==6 -> S_m, else H_mw
            int h = (tid >= 112) ? 1 : 0;
            int j = tid - h * 112;
            int m = j / 7, w = j - m * 7;
            const float4* zp = (const float4*)&zpow[m * ZP + h * 128];
            float a = 0.f;
            if (w == 6) {
#pragma unroll
                for (int k = 0; k < 32; ++k) {
                    float4 a4 = zp[k];
                    a += a4.x + a4.y + a4.z + a4.w;
                }
            } else {
                const float4* vp = (const float4*)&vT[w * ZP + h * 128];
#pragma unroll
                for (int k = 0; k < 32; ++k) {
                    float4 a4 = zp[k], b4 = vp[k];
                    a += a4.x * b4.x + a4.y * b4.y + a4.z * b4.z + a4.w * b4.w;
                }
            }
            sred[tid] = a;
        }
        __syncthreads();
        if (tid < 112) {
            int m = tid / 7, w = tid - m * 7;
            int idx = m * 7 + ((w == 6) ? 0 : (w + 1));   // eval layout: S,H0..H5
            mpart[(size_t)blockIdx.x * 112 + idx] = sred[tid] + sred[tid + 112];
        }
    }
}

// ---------------------------------------------------------------------------
// Kernel 2: fused combine + per-token evaluation (one block = 256 tokens).
// den = sum_m p_m S_m, out_w = sum_m p_m H_mw, p_m = a^m/m!.  Unchanged.
// ---------------------------------------------------------------------------
__global__ __launch_bounds__(256) void qsa_eval(
        const float* __restrict__ zq,
        const float* __restrict__ mpart,
        float* __restrict__ out) {
    __shared__ float sm[112];
    int bk = blockIdx.x;                      // 128 blocks
    int b = bk >> 3;                          // 8 blocks per batch
    int tid = threadIdx.x;
    if (tid < 112) {
        float s = 0.f;
#pragma unroll
        for (int c = 0; c < 8; ++c) s += mpart[(size_t)(b * 8 + c) * 112 + tid];
        sm[tid] = s;
    }
    __syncthreads();

    int t = bk * 256 + tid;
    float a = zq[t];
    float den = 0.f, o0 = 0.f, o1 = 0.f, o2 = 0.f, o3 = 0.f, o4 = 0.f, o5 = 0.f;
    float pw = 1.f;
#pragma unroll
    for (int m = 0; m < NMOM; ++m) {
        const float* mm = sm + m * 7;
        den += pw * mm[0];
        o0 += pw * mm[1]; o1 += pw * mm[2]; o2 += pw * mm[3];
        o3 += pw * mm[4]; o4 += pw * mm[5]; o5 += pw * mm[6];
        pw *= a * (1.0f / (m + 1));           // p_{m+1} = p_m * a/(m+1)
    }
    float inv = 1.0f / den;
    float* o = out + (size_t)t * 6;
    float2* o2p = (float2*)o;                 // t*24B is 8-aligned
    o2p[0] = make_float2(o0 * inv, o1 * inv);
    o2p[1] = make_float2(o2 * inv, o3 * inv);
    o2p[2] = make_float2(o4 * inv, o5 * inv);
}

// ---------------------------------------------------------------------------
extern "C" void kernel_launch(void* const* d_in, const int* in_sizes, int n_in,
                              void* d_out, int out_size, void* d_ws, size_t ws_size,
                              hipStream_t stream) {
    const float* x  = (const float*)d_in[0];
    const float* pq = (const float*)d_in[1];
    const float* pk = (const float*)d_in[2];
    const float* pv = (const float*)d_in[3];
    float* w = (float*)d_ws;
    // ws (floats): zq[32768] | mpart[14336]
    float* zq    = w;
    float* mpart = zq + NTOK;
    float* out   = (float*)d_out;

    qsa_sim<<<dim3(NTOK / 256, 2), 256, 0, stream>>>(x, pq, pk, pv, zq, mpart);
    qsa_eval<<<NTOK / 256, 256, 0, stream>>>(zq, mpart, out);
}